// Round 4
// baseline (1097.162 us; speedup 1.0000x reference)
//
#include <hip/hip_runtime.h>
#include <hip/hip_fp16.h>
#include <math.h>

#define NN 50000
#define NE 800000
#define NEG 0.2f
#define EPS_BN 1e-5f

__device__ __forceinline__ float lrelu(float x){ return x > 0.f ? x : NEG * x; }

// ---------------- CSR build ----------------
__global__ __launch_bounds__(256) void k_deg(const int* __restrict__ dst, int* __restrict__ deg){
  int e = blockIdx.x * 256 + threadIdx.x;
  if (e >= NE) return;
  atomicAdd(&deg[dst[e]], 1);
}

__global__ __launch_bounds__(1024) void k_scan(const int* __restrict__ deg, int* __restrict__ rowptr){
  __shared__ int sums[1024];
  const int CHUNK = (NN + 1023) / 1024;
  int t = threadIdx.x;
  int base = t * CHUNK;
  int s = 0;
  for (int i = 0; i < CHUNK; i++){ int idx = base + i; if (idx < NN) s += deg[idx]; }
  sums[t] = s; __syncthreads();
  for (int off = 1; off < 1024; off <<= 1){
    int v = (t >= off) ? sums[t - off] : 0;
    __syncthreads();
    sums[t] += v;
    __syncthreads();
  }
  int run = (t == 0) ? 0 : sums[t - 1];
  for (int i = 0; i < CHUNK; i++){ int idx = base + i; if (idx < NN){ rowptr[idx] = run; run += deg[idx]; } }
  if (t == 0) rowptr[NN] = NE;
}

__global__ __launch_bounds__(256) void k_fill(const int* __restrict__ src, const int* __restrict__ dst,
                                              const float* __restrict__ ea, const int* __restrict__ rowptr,
                                              int* __restrict__ cnt, int* __restrict__ srcs, float* __restrict__ eas){
  int e = blockIdx.x * 256 + threadIdx.x;
  if (e >= NE) return;
  int d = dst[e];
  int pos = rowptr[d] + atomicAdd(&cnt[d], 1);
  srcs[pos] = src[e];
  eas[pos*3+0] = ea[e*3+0];
  eas[pos*3+1] = ea[e*3+1];
  eas[pos*3+2] = ea[e*3+2];
}

// easum[n] = sum of eas over node n's CSR segment (no atomics; 1 wave/node)
__global__ __launch_bounds__(256) void k_easum(const int* __restrict__ rowptr, const float* __restrict__ eas,
                                               float* __restrict__ easum){
  int n = blockIdx.x * 4 + (threadIdx.x >> 6);
  int c = threadIdx.x & 63;
  if (n >= NN) return;
  int start = rowptr[n], end = rowptr[n + 1];
  float s0 = 0.f, s1 = 0.f, s2 = 0.f;
  for (int p = start + c; p < end; p += 64){
    s0 += eas[p*3+0]; s1 += eas[p*3+1]; s2 += eas[p*3+2];
  }
#pragma unroll
  for (int off = 32; off; off >>= 1){
    s0 += __shfl_down(s0, off, 64);
    s1 += __shfl_down(s1, off, 64);
    s2 += __shfl_down(s2, off, 64);
  }
  if (c == 0){ easum[n*3+0] = s0; easum[n*3+1] = s1; easum[n*3+2] = s2; }
}

// ---------------- input projection (raw, BN applied later in GEMM) ----------------
__global__ __launch_bounds__(256) void k_proj(const float* __restrict__ x, const float* __restrict__ Wp,
                                              const float* __restrict__ bp, float* __restrict__ h0){
  int i = blockIdx.x * 256 + threadIdx.x;
  if (i >= NN * 64) return;
  int n = i >> 6, c = i & 63;
  h0[i] = fmaf(x[n*2+0], Wp[c], fmaf(x[n*2+1], Wp[64+c], bp[c]));
}

// ---------------- BatchNorm stats ----------------
template<int F>
__global__ void k_bn_stats(const float* __restrict__ x, float* __restrict__ sum, float* __restrict__ sq){
  int t = threadIdx.x;  // blockDim == F
  float s = 0.f, s2 = 0.f;
  for (int n = blockIdx.x; n < NN; n += gridDim.x){
    float v = x[(long)n * F + t];
    s += v; s2 += v * v;
  }
  atomicAdd(&sum[t], s);
  atomicAdd(&sq[t], s2);
}

template<int F>
__global__ void k_bn_fin(const float* __restrict__ sum, const float* __restrict__ sq,
                         float* __restrict__ mu, float* __restrict__ rs){
  int t = threadIdx.x;  // blockDim == F
  float m = sum[t] * (1.f / NN);
  float var = sq[t] * (1.f / NN) - m * m;
  mu[t] = m;
  rs[t] = rsqrtf(var + EPS_BN);
}

// ---------------- g[d][h] = sum_c We[d, h*64+c] * ae[h,c] ----------------
template<int H>
__global__ void k_edge_g(const float* __restrict__ We, const float* __restrict__ ae, float* __restrict__ g){
  int t = threadIdx.x;              // blockDim = H*64
  int h = t >> 6, c = t & 63;
  float a = ae[t];
  for (int d = 0; d < 3; d++){
    float p = We[d * (H*64) + t] * a;
    for (int off = 32; off; off >>= 1) p += __shfl_down(p, off, 64);
    if (c == 0) g[d * H + h] = p;
  }
  (void)h;
}

// ---------------- GEMM: C[N,J] = elu(bn(A))[N,K] @ B[K,J], fp16 out ----------------
// 64 rows x full J per 256-thread block; 4x(4*NQ) acc per thread; A read once.
template<int K, int J, bool BNELU>
__global__ __launch_bounds__(256) void k_gemm(const float* __restrict__ A, const float* __restrict__ B,
                                              const float* __restrict__ mu, const float* __restrict__ rs,
                                              __half* __restrict__ C){
  constexpr int NQ = J / 64;
  __shared__ float As[16][68];
  int t = threadIdx.x;
  int row0 = blockIdx.x * 64;
  int lr = t >> 2;                  // 0..63 A-load row
  int lk = (t & 3) * 4;             // A-load k quad
  int tr = t >> 4;                  // 0..15 compute row group
  int tc = t & 15;                  // 0..15 compute col group

  float acc[4][4 * NQ];
#pragma unroll
  for (int i = 0; i < 4; i++)
#pragma unroll
    for (int j = 0; j < 4 * NQ; j++) acc[i][j] = 0.f;

  for (int kt = 0; kt < K; kt += 16){
    float4 av = make_float4(0.f, 0.f, 0.f, 0.f);
    int ar = row0 + lr;
    if (ar < NN){
      av = *(const float4*)&A[(long)ar * K + kt + lk];
      if (BNELU){
        float4 m4 = *(const float4*)&mu[kt + lk];
        float4 r4 = *(const float4*)&rs[kt + lk];
        av.x = (av.x - m4.x) * r4.x; av.x = av.x > 0.f ? av.x : expm1f(av.x);
        av.y = (av.y - m4.y) * r4.y; av.y = av.y > 0.f ? av.y : expm1f(av.y);
        av.z = (av.z - m4.z) * r4.z; av.z = av.z > 0.f ? av.z : expm1f(av.z);
        av.w = (av.w - m4.w) * r4.w; av.w = av.w > 0.f ? av.w : expm1f(av.w);
      }
    }
    __syncthreads();
    As[lk+0][lr] = av.x; As[lk+1][lr] = av.y; As[lk+2][lr] = av.z; As[lk+3][lr] = av.w;
    __syncthreads();
#pragma unroll
    for (int k = 0; k < 16; k++){
      float4 a = *(const float4*)&As[k][tr*4];
#pragma unroll
      for (int q = 0; q < NQ; q++){
        float4 b = *(const float4*)&B[(long)(kt + k) * J + q*64 + tc*4];
        acc[0][q*4+0] = fmaf(a.x, b.x, acc[0][q*4+0]); acc[0][q*4+1] = fmaf(a.x, b.y, acc[0][q*4+1]);
        acc[0][q*4+2] = fmaf(a.x, b.z, acc[0][q*4+2]); acc[0][q*4+3] = fmaf(a.x, b.w, acc[0][q*4+3]);
        acc[1][q*4+0] = fmaf(a.y, b.x, acc[1][q*4+0]); acc[1][q*4+1] = fmaf(a.y, b.y, acc[1][q*4+1]);
        acc[1][q*4+2] = fmaf(a.y, b.z, acc[1][q*4+2]); acc[1][q*4+3] = fmaf(a.y, b.w, acc[1][q*4+3]);
        acc[2][q*4+0] = fmaf(a.z, b.x, acc[2][q*4+0]); acc[2][q*4+1] = fmaf(a.z, b.y, acc[2][q*4+1]);
        acc[2][q*4+2] = fmaf(a.z, b.z, acc[2][q*4+2]); acc[2][q*4+3] = fmaf(a.z, b.w, acc[2][q*4+3]);
        acc[3][q*4+0] = fmaf(a.w, b.x, acc[3][q*4+0]); acc[3][q*4+1] = fmaf(a.w, b.y, acc[3][q*4+1]);
        acc[3][q*4+2] = fmaf(a.w, b.z, acc[3][q*4+2]); acc[3][q*4+3] = fmaf(a.w, b.w, acc[3][q*4+3]);
      }
    }
  }
#pragma unroll
  for (int i = 0; i < 4; i++){
    int r = row0 + tr * 4 + i;
    if (r < NN){
#pragma unroll
      for (int q = 0; q < NQ; q++){
        __half2 h01 = __floats2half2_rn(acc[i][q*4+0], acc[i][q*4+1]);
        __half2 h23 = __floats2half2_rn(acc[i][q*4+2], acc[i][q*4+3]);
        __half2* cp = (__half2*)&C[(long)r * J + q*64 + tc*4];
        cp[0] = h01; cp[1] = h23;
      }
    }
  }
}

// ---------------- per-node attention coefficients ----------------
template<int H>
__global__ void k_attn(const __half* __restrict__ hh, const float* __restrict__ asrc,
                       const float* __restrict__ adst, float* __restrict__ aS, float* __restrict__ aD){
  int n = blockIdx.x;
  int t = threadIdx.x;              // blockDim = H*64
  int h = t >> 6, c = t & 63;
  float v = __half2float(hh[(long)n * (H*64) + t]);
  float ps = v * asrc[t];
  float pd = v * adst[t];
  for (int off = 32; off; off >>= 1){
    ps += __shfl_down(ps, off, 64);
    pd += __shfl_down(pd, off, 64);
  }
  if (c == 0){ aS[n * H + h] = ps; aD[n * H + h] = pd; }
}

// ---------------- fused segment softmax + aggregation (fp16 payload, 2ch threads) ----------------
// Logit phase: wave h computes head-h logits (1 edge/lane), writes chunk-local
// e=exp(l-mc) + chunk (mc,sc) to LDS. Aggregation: thread owns 2 channels of
// head h2, processes edges of its parity (eo), keeps per-thread running
// (m2,den2); chunk partial is rescaled once per chunk.
template<int H, bool ELU>
__global__ void k_gat(const int* __restrict__ rowptr, const int* __restrict__ srcs,
                      const float* __restrict__ eas, const int* __restrict__ deg,
                      const float* __restrict__ easum,
                      const float* __restrict__ aS, const float* __restrict__ aD,
                      const float* __restrict__ g, const __half* __restrict__ hh,
                      const float* __restrict__ bias, float* __restrict__ out){
  constexpr int W = H * 64;
  constexpr int CH2 = W / 2;
  int n = blockIdx.x;
  int t = threadIdx.x;              // blockDim = W
  int h = t >> 6, c = t & 63;       // logit-phase mapping (wave h)
  int ch2 = t & (CH2 - 1);          // aggregation channel pair -> channels 2*ch2, 2*ch2+1
  int eo = t / CH2;                 // edge parity this thread covers
  int h2 = (ch2 * 2) >> 6;          // aggregation head
  int start = rowptr[n], end = rowptr[n + 1];
  float g0 = g[0*H + h], g1 = g[1*H + h], g2 = g[2*H + h];
  float adn = aD[n*H + h];

  __shared__ const __half* s_ptr[64];
  __shared__ float w_lds[H][64];
  __shared__ float ck_m[H], ck_s[H];
  __shared__ float2 red[CH2];

  float m2 = -INFINITY, den2 = 0.f;
  float2 acc = make_float2(0.f, 0.f);

  for (int base0 = start; base0 < end; base0 += 64){
    int len = end - base0; if (len > 64) len = 64;
    // --- logit phase (wave h, one edge per lane) ---
    float l = -INFINITY;
    if (c < len){
      int pos = base0 + c;
      int s = srcs[pos];
      if (h == 0) s_ptr[c] = hh + (long)s * W;
      float lg = aS[s*H + h] + adn + g0*eas[pos*3+0] + g1*eas[pos*3+1] + g2*eas[pos*3+2];
      l = lrelu(lg);
    }
    float mc = l;
#pragma unroll
    for (int off = 32; off; off >>= 1) mc = fmaxf(mc, __shfl_xor(mc, off, 64));
    float e = (c < len) ? __expf(l - mc) : 0.f;
    float sc = e;
#pragma unroll
    for (int off = 32; off; off >>= 1) sc += __shfl_xor(sc, off, 64);
    if (c < len) w_lds[h][c] = e;
    if (c == 0){ ck_m[h] = mc; ck_s[h] = sc; }
    __syncthreads();
    // --- merge chunk into per-thread running state (head h2) ---
    float mc2 = ck_m[h2], sc2 = ck_s[h2];
    float mn = fmaxf(m2, mc2);
    float rr = __expf(m2 - mn);
    float cf = __expf(mc2 - mn);
    den2 = den2 * rr + sc2 * cf;
    m2 = mn;
    // --- aggregation: half2 load + 2 fma per edge (parity eo) ---
    float2 ps = make_float2(0.f, 0.f);
    for (int j = eo; j < len; j += 2){
      float w = w_lds[h2][j];
      const __half* p = s_ptr[j];
      float2 v = __half22float2(*(const __half2*)(p + ch2*2));
      ps.x = fmaf(w, v.x, ps.x);
      ps.y = fmaf(w, v.y, ps.y);
    }
    acc.x = acc.x * rr + ps.x * cf;
    acc.y = acc.y * rr + ps.y * cf;
    __syncthreads();
  }

  // combine the two parity partials
  if (eo == 1) red[ch2] = acc;
  __syncthreads();
  if (eo == 0){
    acc.x += red[ch2].x; acc.y += red[ch2].y;
    // self-loop (fill_value='mean'), head h2
    float g0b = g[0*H + h2], g1b = g[1*H + h2], g2b = g[2*H + h2];
    float adn2 = aD[n*H + h2], asn2 = aS[n*H + h2];
    float dg = (float)deg[n];
    float inv = 1.f / fmaxf(dg, 1.f);
    float ll = asn2 + adn2 + g0b*(easum[n*3+0]*inv) + g1b*(easum[n*3+1]*inv) + g2b*(easum[n*3+2]*inv);
    ll = lrelu(ll);
    float mf = fmaxf(m2, ll);
    float r = __expf(m2 - mf);
    float el = __expf(ll - mf);
    float df = den2 * r + el;
    float2 sv = __half22float2(*(const __half2*)(hh + (long)n * W + ch2*2));
    acc.x = acc.x * r + el * sv.x;
    acc.y = acc.y * r + el * sv.y;
    float invden = 1.f / (df + 1e-16f);
    float2 bv = *(const float2*)&bias[ch2*2];
    acc.x = acc.x * invden + bv.x;
    acc.y = acc.y * invden + bv.y;
    if (ELU){
      acc.x = acc.x > 0.f ? acc.x : expm1f(acc.x);
      acc.y = acc.y > 0.f ? acc.y : expm1f(acc.y);
    }
    *(float2*)&out[(long)n * W + ch2*2] = acc;
  }
}

// ---------------- final linear 64->4 + softmax ----------------
__global__ __launch_bounds__(64) void k_final(const float* __restrict__ h3, const float* __restrict__ Wc,
                                              const float* __restrict__ bc, float* __restrict__ out){
  int n = blockIdx.x;
  int c = threadIdx.x;  // 64
  float v = h3[(long)n * 64 + c];
  float r0 = v * Wc[c*4+0], r1 = v * Wc[c*4+1], r2 = v * Wc[c*4+2], r3 = v * Wc[c*4+3];
  for (int off = 32; off; off >>= 1){
    r0 += __shfl_down(r0, off, 64);
    r1 += __shfl_down(r1, off, 64);
    r2 += __shfl_down(r2, off, 64);
    r3 += __shfl_down(r3, off, 64);
  }
  if (c == 0){
    r0 += bc[0]; r1 += bc[1]; r2 += bc[2]; r3 += bc[3];
    float mm = fmaxf(fmaxf(r0, r1), fmaxf(r2, r3));
    float e0 = __expf(r0 - mm), e1 = __expf(r1 - mm), e2 = __expf(r2 - mm), e3 = __expf(r3 - mm);
    float is = 1.f / (e0 + e1 + e2 + e3);
    out[n*4+0] = e0 * is; out[n*4+1] = e1 * is; out[n*4+2] = e2 * is; out[n*4+3] = e3 * is;
  }
}

extern "C" void kernel_launch(void* const* d_in, const int* in_sizes, int n_in,
                              void* d_out, int out_size, void* d_ws, size_t ws_size,
                              hipStream_t stream){
  const float* x   = (const float*)d_in[0];
  const int*   ei  = (const int*)d_in[1];
  const float* ea  = (const float*)d_in[2];
  const float* Wp  = (const float*)d_in[3];
  const float* bp  = (const float*)d_in[4];
  const float* W1  = (const float*)d_in[5];
  const float* as1 = (const float*)d_in[6];
  const float* ad1 = (const float*)d_in[7];
  const float* We1 = (const float*)d_in[8];
  const float* ae1 = (const float*)d_in[9];
  const float* b1  = (const float*)d_in[10];
  const float* W2  = (const float*)d_in[11];
  const float* as2 = (const float*)d_in[12];
  const float* ad2 = (const float*)d_in[13];
  const float* We2 = (const float*)d_in[14];
  const float* ae2 = (const float*)d_in[15];
  const float* b2  = (const float*)d_in[16];
  const float* W3  = (const float*)d_in[17];
  const float* as3 = (const float*)d_in[18];
  const float* ad3 = (const float*)d_in[19];
  const float* We3 = (const float*)d_in[20];
  const float* ae3 = (const float*)d_in[21];
  const float* b3  = (const float*)d_in[22];
  const float* Wc  = (const float*)d_in[23];
  const float* bc  = (const float*)d_in[24];
  const int* srcI = ei;
  const int* dstI = ei + NE;

  char* base = (char*)d_ws;
  size_t off = 0;
  auto alloc = [&](size_t bytes) -> void* {
    void* p = base + off;
    off += (bytes + 255) & ~(size_t)255;
    return p;
  };
  float*  bufA  = (float*)alloc((size_t)NN * 256 * 4);
  __half* hB    = (__half*)alloc((size_t)NN * 256 * 2);
  int*   deg   = (int*)  alloc((size_t)NN * 4);
  int*   cnt   = (int*)  alloc((size_t)NN * 4);
  int*   rowptr= (int*)  alloc((size_t)(NN + 1) * 4);
  int*   srcs  = (int*)  alloc((size_t)NE * 4);
  float* eas   = (float*)alloc((size_t)NE * 3 * 4);
  float* easum = (float*)alloc((size_t)NN * 3 * 4);
  float* aS    = (float*)alloc((size_t)NN * 4 * 4);
  float* aD    = (float*)alloc((size_t)NN * 4 * 4);
  float* g     = (float*)alloc(256);
  float* bsum  = (float*)alloc(256 * 4);
  float* bsq   = (float*)alloc(256 * 4);
  float* bmu   = (float*)alloc(256 * 4);
  float* brs   = (float*)alloc(256 * 4);
  (void)ws_size; (void)in_sizes; (void)n_in; (void)out_size;

  // CSR build (shared by all layers)
  hipMemsetAsync(deg, 0, (size_t)NN * 4, stream);
  hipMemsetAsync(cnt, 0, (size_t)NN * 4, stream);
  k_deg<<<(NE + 255) / 256, 256, 0, stream>>>(dstI, deg);
  k_scan<<<1, 1024, 0, stream>>>(deg, rowptr);
  k_fill<<<(NE + 255) / 256, 256, 0, stream>>>(srcI, dstI, ea, rowptr, cnt, srcs, eas);
  k_easum<<<(NN + 3) / 4, 256, 0, stream>>>(rowptr, eas, easum);

  // input projection (raw) + BN stats
  k_proj<<<(NN * 64 + 255) / 256, 256, 0, stream>>>(x, Wp, bp, bufA);
  hipMemsetAsync(bsum, 0, 256 * 4, stream);
  hipMemsetAsync(bsq, 0, 256 * 4, stream);
  k_bn_stats<64><<<512, 64, 0, stream>>>(bufA, bsum, bsq);
  k_bn_fin<64><<<1, 64, 0, stream>>>(bsum, bsq, bmu, brs);

  // ---- GAT layer 1 (64 -> 4x64); BN+ELU fused into GEMM A-load ----
  k_edge_g<4><<<1, 256, 0, stream>>>(We1, ae1, g);
  k_gemm<64, 256, true><<<(NN + 63) / 64, 256, 0, stream>>>(bufA, W1, bmu, brs, hB);
  k_attn<4><<<NN, 256, 0, stream>>>(hB, as1, ad1, aS, aD);
  k_gat<4, false><<<NN, 256, 0, stream>>>(rowptr, srcs, eas, deg, easum, aS, aD, g, hB, b1, bufA);
  hipMemsetAsync(bsum, 0, 256 * 4, stream);
  hipMemsetAsync(bsq, 0, 256 * 4, stream);
  k_bn_stats<256><<<512, 256, 0, stream>>>(bufA, bsum, bsq);
  k_bn_fin<256><<<1, 256, 0, stream>>>(bsum, bsq, bmu, brs);

  // ---- GAT layer 2 (256 -> 4x64) ----
  k_edge_g<4><<<1, 256, 0, stream>>>(We2, ae2, g);
  k_gemm<256, 256, true><<<(NN + 63) / 64, 256, 0, stream>>>(bufA, W2, bmu, brs, hB);
  k_attn<4><<<NN, 256, 0, stream>>>(hB, as2, ad2, aS, aD);
  k_gat<4, false><<<NN, 256, 0, stream>>>(rowptr, srcs, eas, deg, easum, aS, aD, g, hB, b2, bufA);
  hipMemsetAsync(bsum, 0, 256 * 4, stream);
  hipMemsetAsync(bsq, 0, 256 * 4, stream);
  k_bn_stats<256><<<512, 256, 0, stream>>>(bufA, bsum, bsq);
  k_bn_fin<256><<<1, 256, 0, stream>>>(bsum, bsq, bmu, brs);

  // ---- GAT layer 3 (256 -> 1x64), ELU fused, no BN after ----
  k_edge_g<1><<<1, 64, 0, stream>>>(We3, ae3, g);
  k_gemm<256, 64, true><<<(NN + 63) / 64, 256, 0, stream>>>(bufA, W3, bmu, brs, hB);
  k_attn<1><<<NN, 64, 0, stream>>>(hB, as3, ad3, aS, aD);
  k_gat<1, true><<<NN, 64, 0, stream>>>(rowptr, srcs, eas, deg, easum, aS, aD, g, hB, b3, bufA);

  // ---- classifier + softmax ----
  k_final<<<NN, 64, 0, stream>>>(bufA, Wc, bc, (float*)d_out);
}

// Round 5
// 1010.221 us; speedup vs baseline: 1.0861x; 1.0861x over previous
//
#include <hip/hip_runtime.h>
#include <hip/hip_fp16.h>
#include <math.h>

#define NN 50000
#define NE 800000
#define NEG 0.2f
#define EPS_BN 1e-5f

__device__ __forceinline__ float lrelu(float x){ return x > 0.f ? x : NEG * x; }

// ---------------- CSR build ----------------
__global__ __launch_bounds__(256) void k_deg(const int* __restrict__ dst, int* __restrict__ deg){
  int e = blockIdx.x * 256 + threadIdx.x;
  if (e >= NE) return;
  atomicAdd(&deg[dst[e]], 1);
}

__global__ __launch_bounds__(1024) void k_scan(const int* __restrict__ deg, int* __restrict__ rowptr){
  __shared__ int sums[1024];
  const int CHUNK = (NN + 1023) / 1024;
  int t = threadIdx.x;
  int base = t * CHUNK;
  int s = 0;
  for (int i = 0; i < CHUNK; i++){ int idx = base + i; if (idx < NN) s += deg[idx]; }
  sums[t] = s; __syncthreads();
  for (int off = 1; off < 1024; off <<= 1){
    int v = (t >= off) ? sums[t - off] : 0;
    __syncthreads();
    sums[t] += v;
    __syncthreads();
  }
  int run = (t == 0) ? 0 : sums[t - 1];
  for (int i = 0; i < CHUNK; i++){ int idx = base + i; if (idx < NN){ rowptr[idx] = run; run += deg[idx]; } }
  if (t == 0) rowptr[NN] = NE;
}

__global__ __launch_bounds__(256) void k_fill(const int* __restrict__ src, const int* __restrict__ dst,
                                              const float* __restrict__ ea, const int* __restrict__ rowptr,
                                              int* __restrict__ cnt, int* __restrict__ srcs, float* __restrict__ eas){
  int e = blockIdx.x * 256 + threadIdx.x;
  if (e >= NE) return;
  int d = dst[e];
  int pos = rowptr[d] + atomicAdd(&cnt[d], 1);
  srcs[pos] = src[e];
  eas[pos*3+0] = ea[e*3+0];
  eas[pos*3+1] = ea[e*3+1];
  eas[pos*3+2] = ea[e*3+2];
}

// easum[n] = sum of eas over node n's CSR segment (no atomics; 1 wave/node)
__global__ __launch_bounds__(256) void k_easum(const int* __restrict__ rowptr, const float* __restrict__ eas,
                                               float* __restrict__ easum){
  int n = blockIdx.x * 4 + (threadIdx.x >> 6);
  int c = threadIdx.x & 63;
  if (n >= NN) return;
  int start = rowptr[n], end = rowptr[n + 1];
  float s0 = 0.f, s1 = 0.f, s2 = 0.f;
  for (int p = start + c; p < end; p += 64){
    s0 += eas[p*3+0]; s1 += eas[p*3+1]; s2 += eas[p*3+2];
  }
#pragma unroll
  for (int off = 32; off; off >>= 1){
    s0 += __shfl_down(s0, off, 64);
    s1 += __shfl_down(s1, off, 64);
    s2 += __shfl_down(s2, off, 64);
  }
  if (c == 0){ easum[n*3+0] = s0; easum[n*3+1] = s1; easum[n*3+2] = s2; }
}

// ---------------- input projection (raw, BN applied later in GEMM) ----------------
__global__ __launch_bounds__(256) void k_proj(const float* __restrict__ x, const float* __restrict__ Wp,
                                              const float* __restrict__ bp, float* __restrict__ h0){
  int i = blockIdx.x * 256 + threadIdx.x;
  if (i >= NN * 64) return;
  int n = i >> 6, c = i & 63;
  h0[i] = fmaf(x[n*2+0], Wp[c], fmaf(x[n*2+1], Wp[64+c], bp[c]));
}

// ---------------- BatchNorm stats ----------------
template<int F>
__global__ void k_bn_stats(const float* __restrict__ x, float* __restrict__ sum, float* __restrict__ sq){
  int t = threadIdx.x;  // blockDim == F
  float s = 0.f, s2 = 0.f;
  for (int n = blockIdx.x; n < NN; n += gridDim.x){
    float v = x[(long)n * F + t];
    s += v; s2 += v * v;
  }
  atomicAdd(&sum[t], s);
  atomicAdd(&sq[t], s2);
}

template<int F>
__global__ void k_bn_fin(const float* __restrict__ sum, const float* __restrict__ sq,
                         float* __restrict__ mu, float* __restrict__ rs){
  int t = threadIdx.x;  // blockDim == F
  float m = sum[t] * (1.f / NN);
  float var = sq[t] * (1.f / NN) - m * m;
  mu[t] = m;
  rs[t] = rsqrtf(var + EPS_BN);
}

// ---------------- g[d][h] = sum_c We[d, h*64+c] * ae[h,c] ----------------
template<int H>
__global__ void k_edge_g(const float* __restrict__ We, const float* __restrict__ ae, float* __restrict__ g){
  int t = threadIdx.x;              // blockDim = H*64
  int h = t >> 6, c = t & 63;
  float a = ae[t];
  for (int d = 0; d < 3; d++){
    float p = We[d * (H*64) + t] * a;
    for (int off = 32; off; off >>= 1) p += __shfl_down(p, off, 64);
    if (c == 0) g[d * H + h] = p;
  }
  (void)h;
}

// ---------------- GEMM: C[N,J] = elu(bn(A))[N,K] @ B[K,J], fp16 out ----------------
// 64x64 tile per 256-thread block, 4x4 acc per thread (16 VGPR acc, no spill).
// A-tile transposed in LDS; B read direct from global (L2-resident).
template<int K, int J, bool BNELU>
__global__ __launch_bounds__(256) void k_gemm(const float* __restrict__ A, const float* __restrict__ B,
                                              const float* __restrict__ mu, const float* __restrict__ rs,
                                              __half* __restrict__ C){
  __shared__ float As[16][68];
  int t = threadIdx.x;
  int row0 = blockIdx.x * 64;
  int col0 = blockIdx.y * 64;
  int lr = t >> 2;                  // 0..63 A-load row
  int lk = (t & 3) * 4;             // A-load k quad
  int tr = t >> 4;                  // 0..15 compute row group
  int tc = t & 15;                  // 0..15 compute col group
  const float* Bp = B + col0 + tc * 4;

  float acc[4][4];
#pragma unroll
  for (int i = 0; i < 4; i++)
#pragma unroll
    for (int j = 0; j < 4; j++) acc[i][j] = 0.f;

  for (int kt = 0; kt < K; kt += 16){
    float4 av = make_float4(0.f, 0.f, 0.f, 0.f);
    int ar = row0 + lr;
    if (ar < NN){
      av = *(const float4*)&A[(long)ar * K + kt + lk];
      if (BNELU){
        float4 m4 = *(const float4*)&mu[kt + lk];
        float4 r4 = *(const float4*)&rs[kt + lk];
        av.x = (av.x - m4.x) * r4.x; av.x = av.x > 0.f ? av.x : expm1f(av.x);
        av.y = (av.y - m4.y) * r4.y; av.y = av.y > 0.f ? av.y : expm1f(av.y);
        av.z = (av.z - m4.z) * r4.z; av.z = av.z > 0.f ? av.z : expm1f(av.z);
        av.w = (av.w - m4.w) * r4.w; av.w = av.w > 0.f ? av.w : expm1f(av.w);
      }
    }
    __syncthreads();
    As[lk+0][lr] = av.x; As[lk+1][lr] = av.y; As[lk+2][lr] = av.z; As[lk+3][lr] = av.w;
    __syncthreads();
#pragma unroll
    for (int k = 0; k < 16; k++){
      float4 a = *(const float4*)&As[k][tr*4];
      float4 b = *(const float4*)&Bp[(long)(kt + k) * J];
      acc[0][0] = fmaf(a.x, b.x, acc[0][0]); acc[0][1] = fmaf(a.x, b.y, acc[0][1]);
      acc[0][2] = fmaf(a.x, b.z, acc[0][2]); acc[0][3] = fmaf(a.x, b.w, acc[0][3]);
      acc[1][0] = fmaf(a.y, b.x, acc[1][0]); acc[1][1] = fmaf(a.y, b.y, acc[1][1]);
      acc[1][2] = fmaf(a.y, b.z, acc[1][2]); acc[1][3] = fmaf(a.y, b.w, acc[1][3]);
      acc[2][0] = fmaf(a.z, b.x, acc[2][0]); acc[2][1] = fmaf(a.z, b.y, acc[2][1]);
      acc[2][2] = fmaf(a.z, b.z, acc[2][2]); acc[2][3] = fmaf(a.z, b.w, acc[2][3]);
      acc[3][0] = fmaf(a.w, b.x, acc[3][0]); acc[3][1] = fmaf(a.w, b.y, acc[3][1]);
      acc[3][2] = fmaf(a.w, b.z, acc[3][2]); acc[3][3] = fmaf(a.w, b.w, acc[3][3]);
    }
  }
  struct H4 { __half2 a, b; };
#pragma unroll
  for (int i = 0; i < 4; i++){
    int r = row0 + tr * 4 + i;
    if (r < NN){
      H4 v;
      v.a = __floats2half2_rn(acc[i][0], acc[i][1]);
      v.b = __floats2half2_rn(acc[i][2], acc[i][3]);
      *(H4*)&C[(long)r * J + col0 + tc * 4] = v;
    }
  }
}

// ---------------- per-node attention coefficients ----------------
template<int H>
__global__ void k_attn(const __half* __restrict__ hh, const float* __restrict__ asrc,
                       const float* __restrict__ adst, float* __restrict__ aS, float* __restrict__ aD){
  int n = blockIdx.x;
  int t = threadIdx.x;              // blockDim = H*64
  int h = t >> 6, c = t & 63;
  float v = __half2float(hh[(long)n * (H*64) + t]);
  float ps = v * asrc[t];
  float pd = v * adst[t];
  for (int off = 32; off; off >>= 1){
    ps += __shfl_down(ps, off, 64);
    pd += __shfl_down(pd, off, 64);
  }
  if (c == 0){ aS[n * H + h] = ps; aD[n * H + h] = pd; }
}

// ---------------- fused segment softmax + aggregation (fp16 payload, 2ch threads) ----------------
template<int H, bool ELU>
__global__ void k_gat(const int* __restrict__ rowptr, const int* __restrict__ srcs,
                      const float* __restrict__ eas, const int* __restrict__ deg,
                      const float* __restrict__ easum,
                      const float* __restrict__ aS, const float* __restrict__ aD,
                      const float* __restrict__ g, const __half* __restrict__ hh,
                      const float* __restrict__ bias, float* __restrict__ out){
  constexpr int W = H * 64;
  constexpr int CH2 = W / 2;
  int n = blockIdx.x;
  int t = threadIdx.x;              // blockDim = W
  int h = t >> 6, c = t & 63;       // logit-phase mapping (wave h)
  int ch2 = t & (CH2 - 1);          // aggregation channel pair -> channels 2*ch2, 2*ch2+1
  int eo = t / CH2;                 // edge parity this thread covers
  int h2 = (ch2 * 2) >> 6;          // aggregation head
  int start = rowptr[n], end = rowptr[n + 1];
  float g0 = g[0*H + h], g1 = g[1*H + h], g2 = g[2*H + h];
  float adn = aD[n*H + h];

  __shared__ const __half* s_ptr[64];
  __shared__ float w_lds[H][64];
  __shared__ float ck_m[H], ck_s[H];
  __shared__ float2 red[CH2];

  float m2 = -INFINITY, den2 = 0.f;
  float2 acc = make_float2(0.f, 0.f);

  for (int base0 = start; base0 < end; base0 += 64){
    int len = end - base0; if (len > 64) len = 64;
    // --- logit phase (wave h, one edge per lane) ---
    float l = -INFINITY;
    if (c < len){
      int pos = base0 + c;
      int s = srcs[pos];
      if (h == 0) s_ptr[c] = hh + (long)s * W;
      float lg = aS[s*H + h] + adn + g0*eas[pos*3+0] + g1*eas[pos*3+1] + g2*eas[pos*3+2];
      l = lrelu(lg);
    }
    float mc = l;
#pragma unroll
    for (int off = 32; off; off >>= 1) mc = fmaxf(mc, __shfl_xor(mc, off, 64));
    float e = (c < len) ? __expf(l - mc) : 0.f;
    float sc = e;
#pragma unroll
    for (int off = 32; off; off >>= 1) sc += __shfl_xor(sc, off, 64);
    if (c < len) w_lds[h][c] = e;
    if (c == 0){ ck_m[h] = mc; ck_s[h] = sc; }
    __syncthreads();
    // --- merge chunk into per-thread running state (head h2) ---
    float mc2 = ck_m[h2], sc2 = ck_s[h2];
    float mn = fmaxf(m2, mc2);
    float rr = __expf(m2 - mn);
    float cf = __expf(mc2 - mn);
    den2 = den2 * rr + sc2 * cf;
    m2 = mn;
    // --- aggregation: half2 load + 2 fma per edge (parity eo) ---
    float2 ps = make_float2(0.f, 0.f);
    for (int j = eo; j < len; j += 2){
      float w = w_lds[h2][j];
      const __half* p = s_ptr[j];
      float2 v = __half22float2(*(const __half2*)(p + ch2*2));
      ps.x = fmaf(w, v.x, ps.x);
      ps.y = fmaf(w, v.y, ps.y);
    }
    acc.x = acc.x * rr + ps.x * cf;
    acc.y = acc.y * rr + ps.y * cf;
    __syncthreads();
  }

  // combine the two parity partials
  if (eo == 1) red[ch2] = acc;
  __syncthreads();
  if (eo == 0){
    acc.x += red[ch2].x; acc.y += red[ch2].y;
    // self-loop (fill_value='mean'), head h2
    float g0b = g[0*H + h2], g1b = g[1*H + h2], g2b = g[2*H + h2];
    float adn2 = aD[n*H + h2], asn2 = aS[n*H + h2];
    float dg = (float)deg[n];
    float inv = 1.f / fmaxf(dg, 1.f);
    float ll = asn2 + adn2 + g0b*(easum[n*3+0]*inv) + g1b*(easum[n*3+1]*inv) + g2b*(easum[n*3+2]*inv);
    ll = lrelu(ll);
    float mf = fmaxf(m2, ll);
    float r = __expf(m2 - mf);
    float el = __expf(ll - mf);
    float df = den2 * r + el;
    float2 sv = __half22float2(*(const __half2*)(hh + (long)n * W + ch2*2));
    acc.x = acc.x * r + el * sv.x;
    acc.y = acc.y * r + el * sv.y;
    float invden = 1.f / (df + 1e-16f);
    float2 bv = *(const float2*)&bias[ch2*2];
    acc.x = acc.x * invden + bv.x;
    acc.y = acc.y * invden + bv.y;
    if (ELU){
      acc.x = acc.x > 0.f ? acc.x : expm1f(acc.x);
      acc.y = acc.y > 0.f ? acc.y : expm1f(acc.y);
    }
    *(float2*)&out[(long)n * W + ch2*2] = acc;
  }
}

// ---------------- final linear 64->4 + softmax ----------------
__global__ __launch_bounds__(64) void k_final(const float* __restrict__ h3, const float* __restrict__ Wc,
                                              const float* __restrict__ bc, float* __restrict__ out){
  int n = blockIdx.x;
  int c = threadIdx.x;  // 64
  float v = h3[(long)n * 64 + c];
  float r0 = v * Wc[c*4+0], r1 = v * Wc[c*4+1], r2 = v * Wc[c*4+2], r3 = v * Wc[c*4+3];
  for (int off = 32; off; off >>= 1){
    r0 += __shfl_down(r0, off, 64);
    r1 += __shfl_down(r1, off, 64);
    r2 += __shfl_down(r2, off, 64);
    r3 += __shfl_down(r3, off, 64);
  }
  if (c == 0){
    r0 += bc[0]; r1 += bc[1]; r2 += bc[2]; r3 += bc[3];
    float mm = fmaxf(fmaxf(r0, r1), fmaxf(r2, r3));
    float e0 = __expf(r0 - mm), e1 = __expf(r1 - mm), e2 = __expf(r2 - mm), e3 = __expf(r3 - mm);
    float is = 1.f / (e0 + e1 + e2 + e3);
    out[n*4+0] = e0 * is; out[n*4+1] = e1 * is; out[n*4+2] = e2 * is; out[n*4+3] = e3 * is;
  }
}

extern "C" void kernel_launch(void* const* d_in, const int* in_sizes, int n_in,
                              void* d_out, int out_size, void* d_ws, size_t ws_size,
                              hipStream_t stream){
  const float* x   = (const float*)d_in[0];
  const int*   ei  = (const int*)d_in[1];
  const float* ea  = (const float*)d_in[2];
  const float* Wp  = (const float*)d_in[3];
  const float* bp  = (const float*)d_in[4];
  const float* W1  = (const float*)d_in[5];
  const float* as1 = (const float*)d_in[6];
  const float* ad1 = (const float*)d_in[7];
  const float* We1 = (const float*)d_in[8];
  const float* ae1 = (const float*)d_in[9];
  const float* b1  = (const float*)d_in[10];
  const float* W2  = (const float*)d_in[11];
  const float* as2 = (const float*)d_in[12];
  const float* ad2 = (const float*)d_in[13];
  const float* We2 = (const float*)d_in[14];
  const float* ae2 = (const float*)d_in[15];
  const float* b2  = (const float*)d_in[16];
  const float* W3  = (const float*)d_in[17];
  const float* as3 = (const float*)d_in[18];
  const float* ad3 = (const float*)d_in[19];
  const float* We3 = (const float*)d_in[20];
  const float* ae3 = (const float*)d_in[21];
  const float* b3  = (const float*)d_in[22];
  const float* Wc  = (const float*)d_in[23];
  const float* bc  = (const float*)d_in[24];
  const int* srcI = ei;
  const int* dstI = ei + NE;

  char* base = (char*)d_ws;
  size_t off = 0;
  auto alloc = [&](size_t bytes) -> void* {
    void* p = base + off;
    off += (bytes + 255) & ~(size_t)255;
    return p;
  };
  float*  bufA  = (float*)alloc((size_t)NN * 256 * 4);
  __half* hB    = (__half*)alloc((size_t)NN * 256 * 2);
  int*   deg   = (int*)  alloc((size_t)NN * 4);
  int*   cnt   = (int*)  alloc((size_t)NN * 4);
  int*   rowptr= (int*)  alloc((size_t)(NN + 1) * 4);
  int*   srcs  = (int*)  alloc((size_t)NE * 4);
  float* eas   = (float*)alloc((size_t)NE * 3 * 4);
  float* easum = (float*)alloc((size_t)NN * 3 * 4);
  float* aS    = (float*)alloc((size_t)NN * 4 * 4);
  float* aD    = (float*)alloc((size_t)NN * 4 * 4);
  float* g     = (float*)alloc(256);
  float* bsum  = (float*)alloc(256 * 4);
  float* bsq   = (float*)alloc(256 * 4);
  float* bmu   = (float*)alloc(256 * 4);
  float* brs   = (float*)alloc(256 * 4);
  (void)ws_size; (void)in_sizes; (void)n_in; (void)out_size;

  // CSR build (shared by all layers)
  hipMemsetAsync(deg, 0, (size_t)NN * 4, stream);
  hipMemsetAsync(cnt, 0, (size_t)NN * 4, stream);
  k_deg<<<(NE + 255) / 256, 256, 0, stream>>>(dstI, deg);
  k_scan<<<1, 1024, 0, stream>>>(deg, rowptr);
  k_fill<<<(NE + 255) / 256, 256, 0, stream>>>(srcI, dstI, ea, rowptr, cnt, srcs, eas);
  k_easum<<<(NN + 3) / 4, 256, 0, stream>>>(rowptr, eas, easum);

  // input projection (raw) + BN stats
  k_proj<<<(NN * 64 + 255) / 256, 256, 0, stream>>>(x, Wp, bp, bufA);
  hipMemsetAsync(bsum, 0, 256 * 4, stream);
  hipMemsetAsync(bsq, 0, 256 * 4, stream);
  k_bn_stats<64><<<512, 64, 0, stream>>>(bufA, bsum, bsq);
  k_bn_fin<64><<<1, 64, 0, stream>>>(bsum, bsq, bmu, brs);

  // ---- GAT layer 1 (64 -> 4x64); BN+ELU fused into GEMM A-load ----
  k_edge_g<4><<<1, 256, 0, stream>>>(We1, ae1, g);
  k_gemm<64, 256, true><<<dim3((NN + 63) / 64, 4), 256, 0, stream>>>(bufA, W1, bmu, brs, hB);
  k_attn<4><<<NN, 256, 0, stream>>>(hB, as1, ad1, aS, aD);
  k_gat<4, false><<<NN, 256, 0, stream>>>(rowptr, srcs, eas, deg, easum, aS, aD, g, hB, b1, bufA);
  hipMemsetAsync(bsum, 0, 256 * 4, stream);
  hipMemsetAsync(bsq, 0, 256 * 4, stream);
  k_bn_stats<256><<<512, 256, 0, stream>>>(bufA, bsum, bsq);
  k_bn_fin<256><<<1, 256, 0, stream>>>(bsum, bsq, bmu, brs);

  // ---- GAT layer 2 (256 -> 4x64) ----
  k_edge_g<4><<<1, 256, 0, stream>>>(We2, ae2, g);
  k_gemm<256, 256, true><<<dim3((NN + 63) / 64, 4), 256, 0, stream>>>(bufA, W2, bmu, brs, hB);
  k_attn<4><<<NN, 256, 0, stream>>>(hB, as2, ad2, aS, aD);
  k_gat<4, false><<<NN, 256, 0, stream>>>(rowptr, srcs, eas, deg, easum, aS, aD, g, hB, b2, bufA);
  hipMemsetAsync(bsum, 0, 256 * 4, stream);
  hipMemsetAsync(bsq, 0, 256 * 4, stream);
  k_bn_stats<256><<<512, 256, 0, stream>>>(bufA, bsum, bsq);
  k_bn_fin<256><<<1, 256, 0, stream>>>(bsum, bsq, bmu, brs);

  // ---- GAT layer 3 (256 -> 1x64), ELU fused, no BN after ----
  k_edge_g<1><<<1, 64, 0, stream>>>(We3, ae3, g);
  k_gemm<256, 64, true><<<dim3((NN + 63) / 64, 1), 256, 0, stream>>>(bufA, W3, bmu, brs, hB);
  k_attn<1><<<NN, 64, 0, stream>>>(hB, as3, ad3, aS, aD);
  k_gat<1, true><<<NN, 64, 0, stream>>>(rowptr, srcs, eas, deg, easum, aS, aD, g, hB, b3, bufA);

  // ---- classifier + softmax ----
  k_final<<<NN, 64, 0, stream>>>(bufA, Wc, bc, (float*)d_out);
}

// Round 6
// 826.613 us; speedup vs baseline: 1.3273x; 1.2221x over previous
//
#include <hip/hip_runtime.h>
#include <hip/hip_fp16.h>
#include <math.h>

#define NN 50000
#define NE 800000
#define NEG 0.2f
#define EPS_BN 1e-5f

typedef _Float16 f16x8 __attribute__((ext_vector_type(8)));
typedef float f32x4 __attribute__((ext_vector_type(4)));
struct H4 { __half2 a, b; };

__device__ __forceinline__ float lrelu(float x){ return x > 0.f ? x : NEG * x; }
__device__ __forceinline__ float elu(float x){ return x > 0.f ? x : expm1f(x); }

// ---------------- CSR build ----------------
__global__ __launch_bounds__(256) void k_deg(const int* __restrict__ dst, int* __restrict__ deg){
  int e = blockIdx.x * 256 + threadIdx.x;
  if (e >= NE) return;
  atomicAdd(&deg[dst[e]], 1);
}

__global__ __launch_bounds__(1024) void k_scan(const int* __restrict__ deg, int* __restrict__ rowptr){
  __shared__ int sums[1024];
  const int CHUNK = (NN + 1023) / 1024;
  int t = threadIdx.x;
  int base = t * CHUNK;
  int s = 0;
  for (int i = 0; i < CHUNK; i++){ int idx = base + i; if (idx < NN) s += deg[idx]; }
  sums[t] = s; __syncthreads();
  for (int off = 1; off < 1024; off <<= 1){
    int v = (t >= off) ? sums[t - off] : 0;
    __syncthreads();
    sums[t] += v;
    __syncthreads();
  }
  int run = (t == 0) ? 0 : sums[t - 1];
  for (int i = 0; i < CHUNK; i++){ int idx = base + i; if (idx < NN){ rowptr[idx] = run; run += deg[idx]; } }
  if (t == 0) rowptr[NN] = NE;
}

__global__ __launch_bounds__(256) void k_fill(const int* __restrict__ src, const int* __restrict__ dst,
                                              const float* __restrict__ ea, const int* __restrict__ rowptr,
                                              int* __restrict__ cnt, int* __restrict__ srcs, float* __restrict__ eas){
  int e = blockIdx.x * 256 + threadIdx.x;
  if (e >= NE) return;
  int d = dst[e];
  int pos = rowptr[d] + atomicAdd(&cnt[d], 1);
  srcs[pos] = src[e];
  eas[pos*3+0] = ea[e*3+0];
  eas[pos*3+1] = ea[e*3+1];
  eas[pos*3+2] = ea[e*3+2];
}

// easum[n] = sum of eas over node n's CSR segment (no atomics; 1 wave/node)
__global__ __launch_bounds__(256) void k_easum(const int* __restrict__ rowptr, const float* __restrict__ eas,
                                               float* __restrict__ easum){
  int n = blockIdx.x * 4 + (threadIdx.x >> 6);
  int c = threadIdx.x & 63;
  if (n >= NN) return;
  int start = rowptr[n], end = rowptr[n + 1];
  float s0 = 0.f, s1 = 0.f, s2 = 0.f;
  for (int p = start + c; p < end; p += 64){
    s0 += eas[p*3+0]; s1 += eas[p*3+1]; s2 += eas[p*3+2];
  }
#pragma unroll
  for (int off = 32; off; off >>= 1){
    s0 += __shfl_down(s0, off, 64);
    s1 += __shfl_down(s1, off, 64);
    s2 += __shfl_down(s2, off, 64);
  }
  if (c == 0){ easum[n*3+0] = s0; easum[n*3+1] = s1; easum[n*3+2] = s2; }
}

// ---------------- input projection (raw, BN applied in k_act) ----------------
__global__ __launch_bounds__(256) void k_proj(const float* __restrict__ x, const float* __restrict__ Wp,
                                              const float* __restrict__ bp, float* __restrict__ h0){
  int i = blockIdx.x * 256 + threadIdx.x;
  if (i >= NN * 64) return;
  int n = i >> 6, c = i & 63;
  h0[i] = fmaf(x[n*2+0], Wp[c], fmaf(x[n*2+1], Wp[64+c], bp[c]));
}

// ---------------- BatchNorm stats ----------------
template<int F>
__global__ void k_bn_stats(const float* __restrict__ x, float* __restrict__ sum, float* __restrict__ sq){
  int t = threadIdx.x;  // blockDim == F
  float s = 0.f, s2 = 0.f;
  for (int n = blockIdx.x; n < NN; n += gridDim.x){
    float v = x[(long)n * F + t];
    s += v; s2 += v * v;
  }
  atomicAdd(&sum[t], s);
  atomicAdd(&sq[t], s2);
}

template<int F>
__global__ void k_bn_fin(const float* __restrict__ sum, const float* __restrict__ sq,
                         float* __restrict__ mu, float* __restrict__ rs){
  int t = threadIdx.x;  // blockDim == F
  float m = sum[t] * (1.f / NN);
  float var = sq[t] * (1.f / NN) - m * m;
  mu[t] = m;
  rs[t] = rsqrtf(var + EPS_BN);
}

// ---------------- BN + ELU + fp16 convert: Ah = elu(bn(x)) ----------------
template<int F>
__global__ __launch_bounds__(256) void k_act(const float* __restrict__ x, const float* __restrict__ mu,
                                             const float* __restrict__ rs, __half* __restrict__ y){
  int i = blockIdx.x * 256 + threadIdx.x;       // quad index
  if (i >= NN * F / 4) return;
  int base = i * 4;
  int f = base & (F - 1);
  float4 v = *(const float4*)&x[base];
  float4 m4 = *(const float4*)&mu[f];
  float4 r4 = *(const float4*)&rs[f];
  v.x = elu((v.x - m4.x) * r4.x);
  v.y = elu((v.y - m4.y) * r4.y);
  v.z = elu((v.z - m4.z) * r4.z);
  v.w = elu((v.w - m4.w) * r4.w);
  H4 o;
  o.a = __floats2half2_rn(v.x, v.y);
  o.b = __floats2half2_rn(v.z, v.w);
  *(H4*)&y[base] = o;
}

// ---------------- weight transpose + fp16: Wt[j][k] = W[k][j] ----------------
__global__ __launch_bounds__(256) void k_wt(const float* __restrict__ W, __half* __restrict__ Wt,
                                            int K, int J){
  int t = blockIdx.x * 256 + threadIdx.x;
  if (t >= K * J) return;
  int k = t / J, j = t % J;
  Wt[(long)j * K + k] = __float2half(W[t]);
}

// ---------------- g[d][h] = sum_c We[d, h*64+c] * ae[h,c] ----------------
template<int H>
__global__ void k_edge_g(const float* __restrict__ We, const float* __restrict__ ae, float* __restrict__ g){
  int t = threadIdx.x;              // blockDim = H*64
  int h = t >> 6, c = t & 63;
  float a = ae[t];
  for (int d = 0; d < 3; d++){
    float p = We[d * (H*64) + t] * a;
    for (int off = 32; off; off >>= 1) p += __shfl_down(p, off, 64);
    if (c == 0) g[d * H + h] = p;
  }
  (void)h;
}

// ---------------- MFMA GEMM: C[N,J] = A[N,K] @ B[K,J], fp16 in/out, fp32 accum ----------------
// 64-row tile, 4 waves; wave w = rows [w*16,w*16+16) x all J cols.
// B k-chunk (32 x J) staged in LDS from pre-transposed Wt[J][K]; A frags direct
// from global (each element read once per block), prefetched one k-step ahead.
template<int K, int J>
__global__ __launch_bounds__(256) void k_gemm_mfma(const __half* __restrict__ A, const __half* __restrict__ Wt,
                                                   __half* __restrict__ C){
  constexpr int NS = J / 16;         // col subtiles per wave
  constexpr int KT = K / 32;         // k-steps
  __shared__ __half Bs[J][40];       // 80B rows: 16B-aligned, <=2-way bank alias
  int t = threadIdx.x;
  int w = t >> 6;
  int l = t & 63;
  int row0 = blockIdx.x * 64;
  int lr = l & 15;                   // A-row / B-col lane part
  int lg = l >> 4;                   // k-group

  f32x4 acc[NS];
#pragma unroll
  for (int s = 0; s < NS; s++) acc[s] = (f32x4){0.f, 0.f, 0.f, 0.f};

  int arow = row0 + w * 16 + lr;
  bool aval = arow < NN;
  const f16x8* Ap = (const f16x8*)(A + (long)arow * K + lg * 8);  // +4 halves*kt*... step below

  f16x8 zf = {(_Float16)0,(_Float16)0,(_Float16)0,(_Float16)0,(_Float16)0,(_Float16)0,(_Float16)0,(_Float16)0};
  f16x8 af_cur = aval ? Ap[0] : zf;   // Ap indexed in units of 8 halves; k-step = 32 halves = 4 units

  for (int kt = 0; kt < KT; kt++){
    int kk = kt * 32;
    // stage B chunk: Bs[c][0..32) = Wt[c][kk..kk+32)
#pragma unroll
    for (int i = 0; i < J / 64; i++){
      int ch = t + 256 * i;
      int c = ch >> 2, q = ch & 3;
      *(uint4*)&Bs[c][q * 8] = *(const uint4*)(Wt + (long)c * K + kk + q * 8);
    }
    __syncthreads();
    f16x8 af_nxt = zf;
    if (aval && kt + 1 < KT) af_nxt = Ap[(kt + 1) * 4];
#pragma unroll
    for (int s = 0; s < NS; s++){
      f16x8 bf = *(const f16x8*)&Bs[s * 16 + lr][lg * 8];
      acc[s] = __builtin_amdgcn_mfma_f32_16x16x32_f16(af_cur, bf, acc[s], 0, 0, 0);
    }
    __syncthreads();
    af_cur = af_nxt;
  }

  int orow = row0 + w * 16 + lg * 4;
#pragma unroll
  for (int s = 0; s < NS; s++){
    int c = s * 16 + lr;
#pragma unroll
    for (int i = 0; i < 4; i++){
      int r = orow + i;
      if (r < NN) C[(long)r * J + c] = __float2half(acc[s][i]);
    }
  }
}

// ---------------- per-node attention coefficients ----------------
template<int H>
__global__ void k_attn(const __half* __restrict__ hh, const float* __restrict__ asrc,
                       const float* __restrict__ adst, float* __restrict__ aS, float* __restrict__ aD){
  int n = blockIdx.x;
  int t = threadIdx.x;              // blockDim = H*64
  int h = t >> 6, c = t & 63;
  float v = __half2float(hh[(long)n * (H*64) + t]);
  float ps = v * asrc[t];
  float pd = v * adst[t];
  for (int off = 32; off; off >>= 1){
    ps += __shfl_down(ps, off, 64);
    pd += __shfl_down(pd, off, 64);
  }
  if (c == 0){ aS[n * H + h] = ps; aD[n * H + h] = pd; }
}

// ---------------- fused segment softmax + aggregation (fp16 payload, 2ch threads) ----------------
template<int H, bool ELU>
__global__ void k_gat(const int* __restrict__ rowptr, const int* __restrict__ srcs,
                      const float* __restrict__ eas, const int* __restrict__ deg,
                      const float* __restrict__ easum,
                      const float* __restrict__ aS, const float* __restrict__ aD,
                      const float* __restrict__ g, const __half* __restrict__ hh,
                      const float* __restrict__ bias, float* __restrict__ out){
  constexpr int W = H * 64;
  constexpr int CH2 = W / 2;
  int n = blockIdx.x;
  int t = threadIdx.x;              // blockDim = W
  int h = t >> 6, c = t & 63;       // logit-phase mapping (wave h)
  int ch2 = t & (CH2 - 1);          // aggregation channel pair
  int eo = t / CH2;                 // edge parity
  int h2 = (ch2 * 2) >> 6;          // aggregation head
  int start = rowptr[n], end = rowptr[n + 1];
  float g0 = g[0*H + h], g1 = g[1*H + h], g2 = g[2*H + h];
  float adn = aD[n*H + h];

  __shared__ const __half* s_ptr[64];
  __shared__ float w_lds[H][64];
  __shared__ float ck_m[H], ck_s[H];
  __shared__ float2 red[CH2];

  float m2 = -INFINITY, den2 = 0.f;
  float2 acc = make_float2(0.f, 0.f);

  for (int base0 = start; base0 < end; base0 += 64){
    int len = end - base0; if (len > 64) len = 64;
    float l = -INFINITY;
    if (c < len){
      int pos = base0 + c;
      int s = srcs[pos];
      if (h == 0) s_ptr[c] = hh + (long)s * W;
      float lg = aS[s*H + h] + adn + g0*eas[pos*3+0] + g1*eas[pos*3+1] + g2*eas[pos*3+2];
      l = lrelu(lg);
    }
    float mc = l;
#pragma unroll
    for (int off = 32; off; off >>= 1) mc = fmaxf(mc, __shfl_xor(mc, off, 64));
    float e = (c < len) ? __expf(l - mc) : 0.f;
    float sc = e;
#pragma unroll
    for (int off = 32; off; off >>= 1) sc += __shfl_xor(sc, off, 64);
    if (c < len) w_lds[h][c] = e;
    if (c == 0){ ck_m[h] = mc; ck_s[h] = sc; }
    __syncthreads();
    float mc2 = ck_m[h2], sc2 = ck_s[h2];
    float mn = fmaxf(m2, mc2);
    float rr = __expf(m2 - mn);
    float cf = __expf(mc2 - mn);
    den2 = den2 * rr + sc2 * cf;
    m2 = mn;
    float2 ps = make_float2(0.f, 0.f);
    for (int j = eo; j < len; j += 2){
      float w = w_lds[h2][j];
      const __half* p = s_ptr[j];
      float2 v = __half22float2(*(const __half2*)(p + ch2*2));
      ps.x = fmaf(w, v.x, ps.x);
      ps.y = fmaf(w, v.y, ps.y);
    }
    acc.x = acc.x * rr + ps.x * cf;
    acc.y = acc.y * rr + ps.y * cf;
    __syncthreads();
  }

  if (eo == 1) red[ch2] = acc;
  __syncthreads();
  if (eo == 0){
    acc.x += red[ch2].x; acc.y += red[ch2].y;
    float g0b = g[0*H + h2], g1b = g[1*H + h2], g2b = g[2*H + h2];
    float adn2 = aD[n*H + h2], asn2 = aS[n*H + h2];
    float dg = (float)deg[n];
    float inv = 1.f / fmaxf(dg, 1.f);
    float ll = asn2 + adn2 + g0b*(easum[n*3+0]*inv) + g1b*(easum[n*3+1]*inv) + g2b*(easum[n*3+2]*inv);
    ll = lrelu(ll);
    float mf = fmaxf(m2, ll);
    float r = __expf(m2 - mf);
    float el = __expf(ll - mf);
    float df = den2 * r + el;
    float2 sv = __half22float2(*(const __half2*)(hh + (long)n * W + ch2*2));
    acc.x = acc.x * r + el * sv.x;
    acc.y = acc.y * r + el * sv.y;
    float invden = 1.f / (df + 1e-16f);
    float2 bv = *(const float2*)&bias[ch2*2];
    acc.x = acc.x * invden + bv.x;
    acc.y = acc.y * invden + bv.y;
    if (ELU){
      acc.x = acc.x > 0.f ? acc.x : expm1f(acc.x);
      acc.y = acc.y > 0.f ? acc.y : expm1f(acc.y);
    }
    *(float2*)&out[(long)n * W + ch2*2] = acc;
  }
}

// ---------------- final linear 64->4 + softmax ----------------
__global__ __launch_bounds__(64) void k_final(const float* __restrict__ h3, const float* __restrict__ Wc,
                                              const float* __restrict__ bc, float* __restrict__ out){
  int n = blockIdx.x;
  int c = threadIdx.x;  // 64
  float v = h3[(long)n * 64 + c];
  float r0 = v * Wc[c*4+0], r1 = v * Wc[c*4+1], r2 = v * Wc[c*4+2], r3 = v * Wc[c*4+3];
  for (int off = 32; off; off >>= 1){
    r0 += __shfl_down(r0, off, 64);
    r1 += __shfl_down(r1, off, 64);
    r2 += __shfl_down(r2, off, 64);
    r3 += __shfl_down(r3, off, 64);
  }
  if (c == 0){
    r0 += bc[0]; r1 += bc[1]; r2 += bc[2]; r3 += bc[3];
    float mm = fmaxf(fmaxf(r0, r1), fmaxf(r2, r3));
    float e0 = __expf(r0 - mm), e1 = __expf(r1 - mm), e2 = __expf(r2 - mm), e3 = __expf(r3 - mm);
    float is = 1.f / (e0 + e1 + e2 + e3);
    out[n*4+0] = e0 * is; out[n*4+1] = e1 * is; out[n*4+2] = e2 * is; out[n*4+3] = e3 * is;
  }
}

extern "C" void kernel_launch(void* const* d_in, const int* in_sizes, int n_in,
                              void* d_out, int out_size, void* d_ws, size_t ws_size,
                              hipStream_t stream){
  const float* x   = (const float*)d_in[0];
  const int*   ei  = (const int*)d_in[1];
  const float* ea  = (const float*)d_in[2];
  const float* Wp  = (const float*)d_in[3];
  const float* bp  = (const float*)d_in[4];
  const float* W1  = (const float*)d_in[5];
  const float* as1 = (const float*)d_in[6];
  const float* ad1 = (const float*)d_in[7];
  const float* We1 = (const float*)d_in[8];
  const float* ae1 = (const float*)d_in[9];
  const float* b1  = (const float*)d_in[10];
  const float* W2  = (const float*)d_in[11];
  const float* as2 = (const float*)d_in[12];
  const float* ad2 = (const float*)d_in[13];
  const float* We2 = (const float*)d_in[14];
  const float* ae2 = (const float*)d_in[15];
  const float* b2  = (const float*)d_in[16];
  const float* W3  = (const float*)d_in[17];
  const float* as3 = (const float*)d_in[18];
  const float* ad3 = (const float*)d_in[19];
  const float* We3 = (const float*)d_in[20];
  const float* ae3 = (const float*)d_in[21];
  const float* b3  = (const float*)d_in[22];
  const float* Wc  = (const float*)d_in[23];
  const float* bc  = (const float*)d_in[24];
  const int* srcI = ei;
  const int* dstI = ei + NE;

  char* base = (char*)d_ws;
  size_t off = 0;
  auto alloc = [&](size_t bytes) -> void* {
    void* p = base + off;
    off += (bytes + 255) & ~(size_t)255;
    return p;
  };
  float*  bufA  = (float*)alloc((size_t)NN * 256 * 4);
  __half* Ah    = (__half*)alloc((size_t)NN * 256 * 2);
  __half* hB    = (__half*)alloc((size_t)NN * 256 * 2);
  __half* Wt1   = (__half*)alloc((size_t)64 * 256 * 2);
  __half* Wt2   = (__half*)alloc((size_t)256 * 256 * 2);
  __half* Wt3   = (__half*)alloc((size_t)256 * 64 * 2);
  int*   deg   = (int*)  alloc((size_t)NN * 4);
  int*   cnt   = (int*)  alloc((size_t)NN * 4);
  int*   rowptr= (int*)  alloc((size_t)(NN + 1) * 4);
  int*   srcs  = (int*)  alloc((size_t)NE * 4);
  float* eas   = (float*)alloc((size_t)NE * 3 * 4);
  float* easum = (float*)alloc((size_t)NN * 3 * 4);
  float* aS    = (float*)alloc((size_t)NN * 4 * 4);
  float* aD    = (float*)alloc((size_t)NN * 4 * 4);
  float* g     = (float*)alloc(256);
  float* bsum  = (float*)alloc(256 * 4);
  float* bsq   = (float*)alloc(256 * 4);
  float* bmu   = (float*)alloc(256 * 4);
  float* brs   = (float*)alloc(256 * 4);
  (void)ws_size; (void)in_sizes; (void)n_in; (void)out_size;

  // CSR build (shared by all layers) + weight conversion
  hipMemsetAsync(deg, 0, (size_t)NN * 4, stream);
  hipMemsetAsync(cnt, 0, (size_t)NN * 4, stream);
  k_deg<<<(NE + 255) / 256, 256, 0, stream>>>(dstI, deg);
  k_scan<<<1, 1024, 0, stream>>>(deg, rowptr);
  k_fill<<<(NE + 255) / 256, 256, 0, stream>>>(srcI, dstI, ea, rowptr, cnt, srcs, eas);
  k_easum<<<(NN + 3) / 4, 256, 0, stream>>>(rowptr, eas, easum);
  k_wt<<<(64 * 256 + 255) / 256, 256, 0, stream>>>(W1, Wt1, 64, 256);
  k_wt<<<(256 * 256 + 255) / 256, 256, 0, stream>>>(W2, Wt2, 256, 256);
  k_wt<<<(256 * 64 + 255) / 256, 256, 0, stream>>>(W3, Wt3, 256, 64);

  // input projection (raw) + BN stats + act
  k_proj<<<(NN * 64 + 255) / 256, 256, 0, stream>>>(x, Wp, bp, bufA);
  hipMemsetAsync(bsum, 0, 256 * 4, stream);
  hipMemsetAsync(bsq, 0, 256 * 4, stream);
  k_bn_stats<64><<<512, 64, 0, stream>>>(bufA, bsum, bsq);
  k_bn_fin<64><<<1, 64, 0, stream>>>(bsum, bsq, bmu, brs);
  k_act<64><<<(NN * 64 / 4 + 255) / 256, 256, 0, stream>>>(bufA, bmu, brs, Ah);

  // ---- GAT layer 1 (64 -> 4x64) ----
  k_edge_g<4><<<1, 256, 0, stream>>>(We1, ae1, g);
  k_gemm_mfma<64, 256><<<(NN + 63) / 64, 256, 0, stream>>>(Ah, Wt1, hB);
  k_attn<4><<<NN, 256, 0, stream>>>(hB, as1, ad1, aS, aD);
  k_gat<4, false><<<NN, 256, 0, stream>>>(rowptr, srcs, eas, deg, easum, aS, aD, g, hB, b1, bufA);
  hipMemsetAsync(bsum, 0, 256 * 4, stream);
  hipMemsetAsync(bsq, 0, 256 * 4, stream);
  k_bn_stats<256><<<512, 256, 0, stream>>>(bufA, bsum, bsq);
  k_bn_fin<256><<<1, 256, 0, stream>>>(bsum, bsq, bmu, brs);
  k_act<256><<<(NN * 256 / 4 + 255) / 256, 256, 0, stream>>>(bufA, bmu, brs, Ah);

  // ---- GAT layer 2 (256 -> 4x64) ----
  k_edge_g<4><<<1, 256, 0, stream>>>(We2, ae2, g);
  k_gemm_mfma<256, 256><<<(NN + 63) / 64, 256, 0, stream>>>(Ah, Wt2, hB);
  k_attn<4><<<NN, 256, 0, stream>>>(hB, as2, ad2, aS, aD);
  k_gat<4, false><<<NN, 256, 0, stream>>>(rowptr, srcs, eas, deg, easum, aS, aD, g, hB, b2, bufA);
  hipMemsetAsync(bsum, 0, 256 * 4, stream);
  hipMemsetAsync(bsq, 0, 256 * 4, stream);
  k_bn_stats<256><<<512, 256, 0, stream>>>(bufA, bsum, bsq);
  k_bn_fin<256><<<1, 256, 0, stream>>>(bsum, bsq, bmu, brs);
  k_act<256><<<(NN * 256 / 4 + 255) / 256, 256, 0, stream>>>(bufA, bmu, brs, Ah);

  // ---- GAT layer 3 (256 -> 1x64), ELU fused in k_gat, no BN after ----
  k_edge_g<1><<<1, 64, 0, stream>>>(We3, ae3, g);
  k_gemm_mfma<256, 64><<<(NN + 63) / 64, 256, 0, stream>>>(Ah, Wt3, hB);
  k_attn<1><<<NN, 64, 0, stream>>>(hB, as3, ad3, aS, aD);
  k_gat<1, true><<<NN, 64, 0, stream>>>(rowptr, srcs, eas, deg, easum, aS, aD, g, hB, b3, bufA);

  // ---- classifier + softmax ----
  k_final<<<NN, 64, 0, stream>>>(bufA, Wc, bc, (float*)d_out);
}

// Round 7
// 710.618 us; speedup vs baseline: 1.5440x; 1.1632x over previous
//
#include <hip/hip_runtime.h>
#include <hip/hip_fp16.h>
#include <math.h>

#define NN 50000
#define NE 800000
#define NEG 0.2f
#define EPS_BN 1e-5f

typedef _Float16 f16x8 __attribute__((ext_vector_type(8)));
typedef float f32x4 __attribute__((ext_vector_type(4)));

struct __align__(16) Edge { int s; float e0, e1, e2; };

__device__ __forceinline__ float lrelu(float x){ return x > 0.f ? x : NEG * x; }
__device__ __forceinline__ float elu(float x){ return x > 0.f ? x : expm1f(x); }

// ---------------- CSR build ----------------
__global__ __launch_bounds__(256) void k_deg(const int* __restrict__ dst, int* __restrict__ deg){
  int e = blockIdx.x * 256 + threadIdx.x;
  if (e >= NE) return;
  atomicAdd(&deg[dst[e]], 1);
}

__global__ __launch_bounds__(1024) void k_scan(const int* __restrict__ deg, int* __restrict__ rowptr){
  __shared__ int sums[1024];
  const int CHUNK = (NN + 1023) / 1024;
  int t = threadIdx.x;
  int base = t * CHUNK;
  int s = 0;
  for (int i = 0; i < CHUNK; i++){ int idx = base + i; if (idx < NN) s += deg[idx]; }
  sums[t] = s; __syncthreads();
  for (int off = 1; off < 1024; off <<= 1){
    int v = (t >= off) ? sums[t - off] : 0;
    __syncthreads();
    sums[t] += v;
    __syncthreads();
  }
  int run = (t == 0) ? 0 : sums[t - 1];
  for (int i = 0; i < CHUNK; i++){ int idx = base + i; if (idx < NN){ rowptr[idx] = run; run += deg[idx]; } }
  if (t == 0) rowptr[NN] = NE;
}

__global__ __launch_bounds__(256) void k_fill(const int* __restrict__ src, const int* __restrict__ dst,
                                              const float* __restrict__ ea, const int* __restrict__ rowptr,
                                              int* __restrict__ cnt, Edge* __restrict__ edges){
  int e = blockIdx.x * 256 + threadIdx.x;
  if (e >= NE) return;
  int d = dst[e];
  int pos = rowptr[d] + atomicAdd(&cnt[d], 1);
  Edge ed;
  ed.s = src[e];
  ed.e0 = ea[e*3+0]; ed.e1 = ea[e*3+1]; ed.e2 = ea[e*3+2];
  edges[pos] = ed;
}

// easum[n] = sum of edge attrs over node n's CSR segment (1 wave/node)
__global__ __launch_bounds__(256) void k_easum(const int* __restrict__ rowptr, const Edge* __restrict__ edges,
                                               float* __restrict__ easum){
  int n = blockIdx.x * 4 + (threadIdx.x >> 6);
  int c = threadIdx.x & 63;
  if (n >= NN) return;
  int start = rowptr[n], end = rowptr[n + 1];
  float s0 = 0.f, s1 = 0.f, s2 = 0.f;
  for (int p = start + c; p < end; p += 64){
    Edge e = edges[p];
    s0 += e.e0; s1 += e.e1; s2 += e.e2;
  }
#pragma unroll
  for (int off = 32; off; off >>= 1){
    s0 += __shfl_down(s0, off, 64);
    s1 += __shfl_down(s1, off, 64);
    s2 += __shfl_down(s2, off, 64);
  }
  if (c == 0){ easum[n*3+0] = s0; easum[n*3+1] = s1; easum[n*3+2] = s2; }
}

// ---------------- input projection (raw, BN applied in GEMM A-load) ----------------
__global__ __launch_bounds__(256) void k_proj(const float* __restrict__ x, const float* __restrict__ Wp,
                                              const float* __restrict__ bp, float* __restrict__ h0){
  int i = blockIdx.x * 256 + threadIdx.x;
  if (i >= NN * 64) return;
  int n = i >> 6, c = i & 63;
  h0[i] = fmaf(x[n*2+0], Wp[c], fmaf(x[n*2+1], Wp[64+c], bp[c]));
}

// ---------------- BatchNorm stats: per-block partials (no atomics/memset) ----------------
template<int F>
__global__ void k_bn_stats(const float* __restrict__ x, float* __restrict__ ps, float* __restrict__ pq){
  int t = threadIdx.x;  // blockDim == F
  float s = 0.f, s2 = 0.f;
  for (int n = blockIdx.x; n < NN; n += 512){
    float v = x[(long)n * F + t];
    s += v; s2 += v * v;
  }
  ps[blockIdx.x * F + t] = s;
  pq[blockIdx.x * F + t] = s2;
}

template<int F>
__global__ void k_bn_fin(const float* __restrict__ ps, const float* __restrict__ pq,
                         float* __restrict__ mu, float* __restrict__ rs){
  int t = threadIdx.x;  // blockDim == F
  float s = 0.f, s2 = 0.f;
  for (int b = 0; b < 512; b++){ s += ps[b * F + t]; s2 += pq[b * F + t]; }
  float m = s * (1.f / NN);
  float var = s2 * (1.f / NN) - m * m;
  mu[t] = m;
  rs[t] = rsqrtf(var + EPS_BN);
}

// ---------------- weight transpose + fp16: Wt[j][k] = W[k][j] ----------------
__global__ __launch_bounds__(256) void k_wt(const float* __restrict__ W, __half* __restrict__ Wt,
                                            int K, int J){
  int t = blockIdx.x * 256 + threadIdx.x;
  if (t >= K * J) return;
  int k = t / J, j = t % J;
  Wt[(long)j * K + k] = __float2half(W[t]);
}

// ---------------- g[d][h] = sum_c We[d, h*64+c] * ae[h,c] ----------------
template<int H>
__global__ void k_edge_g(const float* __restrict__ We, const float* __restrict__ ae, float* __restrict__ g){
  int t = threadIdx.x;              // blockDim = H*64
  int h = t >> 6, c = t & 63;
  float a = ae[t];
  for (int d = 0; d < 3; d++){
    float p = We[d * (H*64) + t] * a;
    for (int off = 32; off; off >>= 1) p += __shfl_down(p, off, 64);
    if (c == 0) g[d * H + h] = p;
  }
  (void)h;
}

// ---------------- MFMA GEMM with fused BN+ELU on A and fused attn-coeff epilogue ----------------
// C[N,J] = elu(bn(A))[N,K] @ W[K,J]; also aS[r,h] = sum_c C32[r,c]*asrc[c], aD likewise.
// 64-row tile, 4 waves; wave w = rows [w*16, w*16+16) x all J cols.
template<int K, int J>
__global__ __launch_bounds__(256) void k_gemm_mfma(const float* __restrict__ A, const __half* __restrict__ Wt,
                                                   const float* __restrict__ mu, const float* __restrict__ rs,
                                                   const float* __restrict__ asrc, const float* __restrict__ adst,
                                                   __half* __restrict__ C, float* __restrict__ aS,
                                                   float* __restrict__ aD){
  constexpr int NS = J / 16;
  constexpr int KT = K / 32;
  constexpr int HH = J / 64;
  __shared__ __half Bs[J][40];
  int t = threadIdx.x;
  int w = t >> 6;
  int l = t & 63;
  int row0 = blockIdx.x * 64;
  int lr = l & 15;
  int lg = l >> 4;

  f32x4 acc[NS];
#pragma unroll
  for (int s = 0; s < NS; s++) acc[s] = (f32x4){0.f, 0.f, 0.f, 0.f};

  int arow = row0 + w * 16 + lr;
  bool aval = arow < NN;
  const float* Arow = A + (long)arow * K;

  auto loadA = [&](int kt) -> f16x8 {
    f16x8 r;
#pragma unroll
    for (int k = 0; k < 8; k++) r[k] = (_Float16)0.f;
    if (aval){
      int k0 = kt * 32 + lg * 8;
      float4 q0 = *(const float4*)&Arow[k0];
      float4 q1 = *(const float4*)&Arow[k0 + 4];
      float4 m0 = *(const float4*)&mu[k0];
      float4 m1 = *(const float4*)&mu[k0 + 4];
      float4 r0 = *(const float4*)&rs[k0];
      float4 r1 = *(const float4*)&rs[k0 + 4];
      r[0] = (_Float16)elu((q0.x - m0.x) * r0.x);
      r[1] = (_Float16)elu((q0.y - m0.y) * r0.y);
      r[2] = (_Float16)elu((q0.z - m0.z) * r0.z);
      r[3] = (_Float16)elu((q0.w - m0.w) * r0.w);
      r[4] = (_Float16)elu((q1.x - m1.x) * r1.x);
      r[5] = (_Float16)elu((q1.y - m1.y) * r1.y);
      r[6] = (_Float16)elu((q1.z - m1.z) * r1.z);
      r[7] = (_Float16)elu((q1.w - m1.w) * r1.w);
    }
    return r;
  };

  f16x8 af_cur = loadA(0);

  for (int kt = 0; kt < KT; kt++){
    int kk = kt * 32;
#pragma unroll
    for (int i = 0; i < J / 64; i++){
      int ch = t + 256 * i;
      int c = ch >> 2, q = ch & 3;
      *(uint4*)&Bs[c][q * 8] = *(const uint4*)(Wt + (long)c * K + kk + q * 8);
    }
    __syncthreads();
    f16x8 af_nxt;
#pragma unroll
    for (int k = 0; k < 8; k++) af_nxt[k] = (_Float16)0.f;
    if (kt + 1 < KT) af_nxt = loadA(kt + 1);
#pragma unroll
    for (int s = 0; s < NS; s++){
      f16x8 bf = *(const f16x8*)&Bs[s * 16 + lr][lg * 8];
      acc[s] = __builtin_amdgcn_mfma_f32_16x16x32_f16(af_cur, bf, acc[s], 0, 0, 0);
    }
    __syncthreads();
    af_cur = af_nxt;
  }

  // ---- epilogue: C write (fp16) + attn coefficients ----
  int orow = row0 + w * 16 + lg * 4;
  float sA[HH][4], dA[HH][4];
#pragma unroll
  for (int hd = 0; hd < HH; hd++)
#pragma unroll
    for (int i = 0; i < 4; i++){ sA[hd][i] = 0.f; dA[hd][i] = 0.f; }

#pragma unroll
  for (int s = 0; s < NS; s++){
    int cidx = s * 16 + lr;
    int hd = s >> 2;
    float a1 = asrc[cidx], a2 = adst[cidx];
#pragma unroll
    for (int i = 0; i < 4; i++){
      float v = acc[s][i];
      sA[hd][i] = fmaf(v, a1, sA[hd][i]);
      dA[hd][i] = fmaf(v, a2, dA[hd][i]);
      int r = orow + i;
      if (r < NN) C[(long)r * J + cidx] = __float2half(v);
    }
  }
#pragma unroll
  for (int off = 1; off <= 8; off <<= 1){
#pragma unroll
    for (int hd = 0; hd < HH; hd++)
#pragma unroll
      for (int i = 0; i < 4; i++){
        sA[hd][i] += __shfl_xor(sA[hd][i], off, 64);
        dA[hd][i] += __shfl_xor(dA[hd][i], off, 64);
      }
  }
  if (lr == 0){
#pragma unroll
    for (int i = 0; i < 4; i++){
      int r = orow + i;
      if (r < NN){
#pragma unroll
        for (int hd = 0; hd < HH; hd++){
          aS[r * HH + hd] = sA[hd][i];
          aD[r * HH + hd] = dA[hd][i];
        }
      }
    }
  }
}

// ---------------- fused segment softmax + aggregation ----------------
// Logit phase: wave h computes head-h logits (1 edge/lane) -> w_lds + chunk (m,s).
// Aggregation: thread owns 8 fp16 channels (16B loads), covers edge-slots j = es mod 8.
template<int H, bool ELU>
__global__ void k_gat(const int* __restrict__ rowptr, const Edge* __restrict__ edges,
                      const int* __restrict__ deg, const float* __restrict__ easum,
                      const float* __restrict__ aS, const float* __restrict__ aD,
                      const float* __restrict__ g, const __half* __restrict__ hh,
                      const float* __restrict__ bias, float* __restrict__ out){
  constexpr int W = H * 64;
  constexpr int CG = W / 8;          // channel groups of 8
  int n = blockIdx.x;
  int t = threadIdx.x;               // blockDim = W
  int h = t >> 6, c = t & 63;        // logit mapping (wave per head)
  int es = t / CG;                   // edge-slot 0..7
  int ch8 = t & (CG - 1);            // channel group
  int h2 = (ch8 * 8) >> 6;           // this thread's aggregation head
  int start = rowptr[n], end = rowptr[n + 1];
  float g0 = g[0*H + h], g1 = g[1*H + h], g2 = g[2*H + h];
  float adn = aD[n*H + h];

  __shared__ const __half* s_ptr[64];
  __shared__ float w_lds[H][68];
  __shared__ float ck_m[H], ck_s[H];
  __shared__ float red[(H == 4) ? 4 : 1][CG][9];

  float m2 = -INFINITY, den2 = 0.f;
  float acc[8];
#pragma unroll
  for (int k = 0; k < 8; k++) acc[k] = 0.f;

  for (int base0 = start; base0 < end; base0 += 64){
    int len = end - base0; if (len > 64) len = 64;
    // --- logit phase ---
    float l = -INFINITY;
    if (c < len){
      Edge e = edges[base0 + c];
      if (h == 0) s_ptr[c] = hh + (long)e.s * W;
      float lg_ = aS[e.s*H + h] + adn + g0*e.e0 + g1*e.e1 + g2*e.e2;
      l = lrelu(lg_);
    }
    float mc = l;
#pragma unroll
    for (int off = 32; off; off >>= 1) mc = fmaxf(mc, __shfl_xor(mc, off, 64));
    float ev = (c < len) ? __expf(l - mc) : 0.f;
    float sc = ev;
#pragma unroll
    for (int off = 32; off; off >>= 1) sc += __shfl_xor(sc, off, 64);
    if (c < len) w_lds[h][c] = ev;
    if (c == 0){ ck_m[h] = mc; ck_s[h] = sc; }
    __syncthreads();
    // --- merge chunk into running state ---
    float mc2 = ck_m[h2], sc2 = ck_s[h2];
    float mn = fmaxf(m2, mc2);
    float rr = __expf(m2 - mn);
    float cf = __expf(mc2 - mn);
    den2 = den2 * rr + sc2 * cf;
    m2 = mn;
    // --- aggregation: 16B gather + 8 fma per edge-slot ---
    float ps[8];
#pragma unroll
    for (int k = 0; k < 8; k++) ps[k] = 0.f;
    for (int j = es; j < len; j += 8){
      float wj = w_lds[h2][j];
      f16x8 v = *(const f16x8*)(s_ptr[j] + ch8 * 8);
#pragma unroll
      for (int k = 0; k < 8; k++) ps[k] = fmaf(wj, (float)v[k], ps[k]);
    }
#pragma unroll
    for (int k = 0; k < 8; k++) acc[k] = acc[k] * rr + ps[k] * cf;
    __syncthreads();
  }

  // --- combine edge-slot partials ---
  if constexpr (H == 4){
#pragma unroll
    for (int k = 0; k < 8; k++) acc[k] += __shfl_xor(acc[k], 32, 64);
    int lane = t & 63;
    if (lane < 32){
#pragma unroll
      for (int k = 0; k < 8; k++) red[t >> 6][lane][k] = acc[k];
    }
    __syncthreads();
    if (t < 32){
#pragma unroll
      for (int k = 0; k < 8; k++)
        acc[k] = red[0][t][k] + red[1][t][k] + red[2][t][k] + red[3][t][k];
    }
  } else {
#pragma unroll
    for (int k = 0; k < 8; k++){
      acc[k] += __shfl_xor(acc[k], 8, 64);
      acc[k] += __shfl_xor(acc[k], 16, 64);
      acc[k] += __shfl_xor(acc[k], 32, 64);
    }
  }

  if (t < CG){
    int hf = (t * 8) >> 6;   // == this thread's h2
    float g0b = g[0*H + hf], g1b = g[1*H + hf], g2b = g[2*H + hf];
    float adn2 = aD[n*H + hf], asn2 = aS[n*H + hf];
    float dg = (float)deg[n];
    float inv = 1.f / fmaxf(dg, 1.f);
    float ll = asn2 + adn2 + g0b*(easum[n*3+0]*inv) + g1b*(easum[n*3+1]*inv) + g2b*(easum[n*3+2]*inv);
    ll = lrelu(ll);
    float mf = fmaxf(m2, ll);
    float r = __expf(m2 - mf);
    float el = __expf(ll - mf);
    float df = den2 * r + el;
    f16x8 sv = *(const f16x8*)(hh + (long)n * W + t * 8);
#pragma unroll
    for (int k = 0; k < 8; k++) acc[k] = acc[k] * r + el * (float)sv[k];
    float invden = 1.f / (df + 1e-16f);
    float4 b0 = *(const float4*)&bias[t*8];
    float4 b1 = *(const float4*)&bias[t*8 + 4];
    float bb[8] = {b0.x, b0.y, b0.z, b0.w, b1.x, b1.y, b1.z, b1.w};
#pragma unroll
    for (int k = 0; k < 8; k++){
      acc[k] = acc[k] * invden + bb[k];
      if (ELU) acc[k] = acc[k] > 0.f ? acc[k] : expm1f(acc[k]);
    }
    float4 o0 = make_float4(acc[0], acc[1], acc[2], acc[3]);
    float4 o1 = make_float4(acc[4], acc[5], acc[6], acc[7]);
    *(float4*)&out[(long)n * W + t*8] = o0;
    *(float4*)&out[(long)n * W + t*8 + 4] = o1;
  }
}

// ---------------- final linear 64->4 + softmax ----------------
__global__ __launch_bounds__(64) void k_final(const float* __restrict__ h3, const float* __restrict__ Wc,
                                              const float* __restrict__ bc, float* __restrict__ out){
  int n = blockIdx.x;
  int c = threadIdx.x;  // 64
  float v = h3[(long)n * 64 + c];
  float r0 = v * Wc[c*4+0], r1 = v * Wc[c*4+1], r2 = v * Wc[c*4+2], r3 = v * Wc[c*4+3];
  for (int off = 32; off; off >>= 1){
    r0 += __shfl_down(r0, off, 64);
    r1 += __shfl_down(r1, off, 64);
    r2 += __shfl_down(r2, off, 64);
    r3 += __shfl_down(r3, off, 64);
  }
  if (c == 0){
    r0 += bc[0]; r1 += bc[1]; r2 += bc[2]; r3 += bc[3];
    float mm = fmaxf(fmaxf(r0, r1), fmaxf(r2, r3));
    float e0 = __expf(r0 - mm), e1 = __expf(r1 - mm), e2 = __expf(r2 - mm), e3 = __expf(r3 - mm);
    float is = 1.f / (e0 + e1 + e2 + e3);
    out[n*4+0] = e0 * is; out[n*4+1] = e1 * is; out[n*4+2] = e2 * is; out[n*4+3] = e3 * is;
  }
}

extern "C" void kernel_launch(void* const* d_in, const int* in_sizes, int n_in,
                              void* d_out, int out_size, void* d_ws, size_t ws_size,
                              hipStream_t stream){
  const float* x   = (const float*)d_in[0];
  const int*   ei  = (const int*)d_in[1];
  const float* ea  = (const float*)d_in[2];
  const float* Wp  = (const float*)d_in[3];
  const float* bp  = (const float*)d_in[4];
  const float* W1  = (const float*)d_in[5];
  const float* as1 = (const float*)d_in[6];
  const float* ad1 = (const float*)d_in[7];
  const float* We1 = (const float*)d_in[8];
  const float* ae1 = (const float*)d_in[9];
  const float* b1  = (const float*)d_in[10];
  const float* W2  = (const float*)d_in[11];
  const float* as2 = (const float*)d_in[12];
  const float* ad2 = (const float*)d_in[13];
  const float* We2 = (const float*)d_in[14];
  const float* ae2 = (const float*)d_in[15];
  const float* b2  = (const float*)d_in[16];
  const float* W3  = (const float*)d_in[17];
  const float* as3 = (const float*)d_in[18];
  const float* ad3 = (const float*)d_in[19];
  const float* We3 = (const float*)d_in[20];
  const float* ae3 = (const float*)d_in[21];
  const float* b3  = (const float*)d_in[22];
  const float* Wc  = (const float*)d_in[23];
  const float* bc  = (const float*)d_in[24];
  const int* srcI = ei;
  const int* dstI = ei + NE;

  char* base = (char*)d_ws;
  size_t off = 0;
  auto alloc = [&](size_t bytes) -> void* {
    void* p = base + off;
    off += (bytes + 255) & ~(size_t)255;
    return p;
  };
  float*  bufA  = (float*)alloc((size_t)NN * 256 * 4);
  __half* hB    = (__half*)alloc((size_t)NN * 256 * 2);
  __half* Wt1   = (__half*)alloc((size_t)64 * 256 * 2);
  __half* Wt2   = (__half*)alloc((size_t)256 * 256 * 2);
  __half* Wt3   = (__half*)alloc((size_t)256 * 64 * 2);
  int*   deg   = (int*)  alloc((size_t)NN * 4);
  int*   cnt   = (int*)  alloc((size_t)NN * 4);
  int*   rowptr= (int*)  alloc((size_t)(NN + 1) * 4);
  Edge*  edges = (Edge*) alloc((size_t)NE * sizeof(Edge));
  float* easum = (float*)alloc((size_t)NN * 3 * 4);
  float* aS    = (float*)alloc((size_t)NN * 4 * 4);
  float* aD    = (float*)alloc((size_t)NN * 4 * 4);
  float* g     = (float*)alloc(256);
  float* pbs   = (float*)alloc((size_t)512 * 256 * 4);
  float* pbq   = (float*)alloc((size_t)512 * 256 * 4);
  float* bmu   = (float*)alloc(256 * 4);
  float* brs   = (float*)alloc(256 * 4);
  (void)ws_size; (void)in_sizes; (void)n_in; (void)out_size;

  // CSR build (shared by all layers) + weight conversion
  hipMemsetAsync(deg, 0, (size_t)NN * 4, stream);
  hipMemsetAsync(cnt, 0, (size_t)NN * 4, stream);
  k_deg<<<(NE + 255) / 256, 256, 0, stream>>>(dstI, deg);
  k_scan<<<1, 1024, 0, stream>>>(deg, rowptr);
  k_fill<<<(NE + 255) / 256, 256, 0, stream>>>(srcI, dstI, ea, rowptr, cnt, edges);
  k_easum<<<(NN + 3) / 4, 256, 0, stream>>>(rowptr, edges, easum);
  k_wt<<<(64 * 256 + 255) / 256, 256, 0, stream>>>(W1, Wt1, 64, 256);
  k_wt<<<(256 * 256 + 255) / 256, 256, 0, stream>>>(W2, Wt2, 256, 256);
  k_wt<<<(256 * 64 + 255) / 256, 256, 0, stream>>>(W3, Wt3, 256, 64);

  // input projection (raw) + BN stats
  k_proj<<<(NN * 64 + 255) / 256, 256, 0, stream>>>(x, Wp, bp, bufA);
  k_bn_stats<64><<<512, 64, 0, stream>>>(bufA, pbs, pbq);
  k_bn_fin<64><<<1, 64, 0, stream>>>(pbs, pbq, bmu, brs);

  // ---- GAT layer 1 (64 -> 4x64) ----
  k_edge_g<4><<<1, 256, 0, stream>>>(We1, ae1, g);
  k_gemm_mfma<64, 256><<<(NN + 63) / 64, 256, 0, stream>>>(bufA, Wt1, bmu, brs, as1, ad1, hB, aS, aD);
  k_gat<4, false><<<NN, 256, 0, stream>>>(rowptr, edges, deg, easum, aS, aD, g, hB, b1, bufA);
  k_bn_stats<256><<<512, 256, 0, stream>>>(bufA, pbs, pbq);
  k_bn_fin<256><<<1, 256, 0, stream>>>(pbs, pbq, bmu, brs);

  // ---- GAT layer 2 (256 -> 4x64) ----
  k_edge_g<4><<<1, 256, 0, stream>>>(We2, ae2, g);
  k_gemm_mfma<256, 256><<<(NN + 63) / 64, 256, 0, stream>>>(bufA, Wt2, bmu, brs, as2, ad2, hB, aS, aD);
  k_gat<4, false><<<NN, 256, 0, stream>>>(rowptr, edges, deg, easum, aS, aD, g, hB, b2, bufA);
  k_bn_stats<256><<<512, 256, 0, stream>>>(bufA, pbs, pbq);
  k_bn_fin<256><<<1, 256, 0, stream>>>(pbs, pbq, bmu, brs);

  // ---- GAT layer 3 (256 -> 1x64), ELU fused in k_gat, no BN after ----
  k_edge_g<1><<<1, 64, 0, stream>>>(We3, ae3, g);
  k_gemm_mfma<256, 64><<<(NN + 63) / 64, 256, 0, stream>>>(bufA, Wt3, bmu, brs, as3, ad3, hB, aS, aD);
  k_gat<1, true><<<NN, 64, 0, stream>>>(rowptr, edges, deg, easum, aS, aD, g, hB, b3, bufA);

  // ---- classifier + softmax ----
  k_final<<<NN, 64, 0, stream>>>(bufA, Wc, bc, (float*)d_out);
}